// Round 2
// baseline (962.156 us; speedup 1.0000x reference)
//
#include <hip/hip_runtime.h>
#include <float.h>

#define BATCH 4
#define LSEQ  2048
#define DMODEL 512
#define NH    8
#define DHD   64
#define NSAMP 40
#define NTOP  40
#define QK_SCALE 0.125f   // 1/sqrt(64)

// ---------------------------------------------------------------------------
// K1: fp32 QKV GEMM (vector ALU — no fp32 MFMA on CDNA4, and M-selection
// needs fp32-exact Q/K).  C = A @ W^T + b,  A:(8192x512), W:(512x512).
// Tile 128x128, KSTEP=32, 8x8 micro-tile/thread, transpose-in-LDS so the
// inner loop is ds_read_b128 + rank-1 FMA updates.
// grid = (64, 4, 3); z selects Q/K/V. Output scattered fp32 to (b,h,l,d).
// ---------------------------------------------------------------------------
#define KSTEP 32

__global__ __launch_bounds__(256) void qkv_gemm_f32(
    const float* __restrict__ x, const float* __restrict__ ctxin,
    const float* __restrict__ Wq, const float* __restrict__ bq,
    const float* __restrict__ Wk, const float* __restrict__ bk,
    const float* __restrict__ Wv, const float* __restrict__ bv,
    float* __restrict__ Qt, float* __restrict__ Kt, float* __restrict__ Vt)
{
    const int z = blockIdx.z;
    const float* __restrict__ A    = (z == 0) ? x  : ctxin;
    const float* __restrict__ W    = (z == 0) ? Wq : (z == 1 ? Wk : Wv);
    const float* __restrict__ bias = (z == 0) ? bq : (z == 1 ? bk : bv);
    float*       __restrict__ Out  = (z == 0) ? Qt : (z == 1 ? Kt : Vt);

    __shared__ float As[KSTEP][128 + 4];   // [k][m], padded
    __shared__ float Ws[KSTEP][128 + 4];   // [k][n], padded

    const int tid = threadIdx.x;
    const int tn  = tid & 15;            // n-group 0..15
    const int tm  = tid >> 4;            // m-group 0..15
    const int m0  = blockIdx.x * 128;
    const int n0  = blockIdx.y * 128;

    const int srow = tid >> 3;           // 0..31 staging row
    const int sc4  = tid & 7;            // 0..7  staging float4-col

    float acc[8][8] = {};

    for (int k0 = 0; k0 < DMODEL; k0 += KSTEP) {
        __syncthreads();
#pragma unroll
        for (int rr = 0; rr < 4; ++rr) {
            const int r = srow + rr * 32;
            const float4 av = *reinterpret_cast<const float4*>(
                A + (size_t)(m0 + r) * DMODEL + k0 + sc4 * 4);
            const float4 wv = *reinterpret_cast<const float4*>(
                W + (size_t)(n0 + r) * DMODEL + k0 + sc4 * 4);
            As[sc4 * 4 + 0][r] = av.x; As[sc4 * 4 + 1][r] = av.y;
            As[sc4 * 4 + 2][r] = av.z; As[sc4 * 4 + 3][r] = av.w;
            Ws[sc4 * 4 + 0][r] = wv.x; Ws[sc4 * 4 + 1][r] = wv.y;
            Ws[sc4 * 4 + 2][r] = wv.z; Ws[sc4 * 4 + 3][r] = wv.w;
        }
        __syncthreads();
#pragma unroll
        for (int kk = 0; kk < KSTEP; ++kk) {
            float a[8], b[8];
            *reinterpret_cast<float4*>(&a[0]) =
                *reinterpret_cast<const float4*>(&As[kk][tm * 8]);
            *reinterpret_cast<float4*>(&a[4]) =
                *reinterpret_cast<const float4*>(&As[kk][tm * 8 + 4]);
            *reinterpret_cast<float4*>(&b[0]) =
                *reinterpret_cast<const float4*>(&Ws[kk][tn * 8]);
            *reinterpret_cast<float4*>(&b[4]) =
                *reinterpret_cast<const float4*>(&Ws[kk][tn * 8 + 4]);
#pragma unroll
            for (int i = 0; i < 8; ++i)
#pragma unroll
                for (int j = 0; j < 8; ++j)
                    acc[i][j] = fmaf(a[i], b[j], acc[i][j]);
        }
    }

    const int mbase = m0 + tm * 8;
    const int nbase = n0 + tn * 8;
#pragma unroll
    for (int i = 0; i < 8; ++i) {
        const int m = mbase + i;
        const int b = m >> 11, l = m & (LSEQ - 1);
#pragma unroll
        for (int j = 0; j < 8; ++j) {
            const int n = nbase + j;
            const int h = n >> 6, d = n & 63;
            Out[(((size_t)(b * NH + h) * LSEQ) + l) * DHD + d] = acc[i][j] + bias[n];
        }
    }
}

// ---------------------------------------------------------------------------
// K2: sampled sparsity measure M = max_s(q.k_s) - sum_s(q.k_s)/L_enc.
// One wave per query row; lane = d.
// ---------------------------------------------------------------------------
__global__ __launch_bounds__(256) void score_kernel(
    const float* __restrict__ Qt, const float* __restrict__ Kt,
    const int* __restrict__ idxs, float* __restrict__ M)
{
    const int wid  = blockIdx.x * 4 + (threadIdx.x >> 6);  // = bh*LSEQ + l
    const int lane = threadIdx.x & 63;
    const int l    = wid & (LSEQ - 1);
    const int bh   = wid >> 11;

    const float q = Qt[(size_t)wid * DHD + lane];
    const float* Kb = Kt + (size_t)bh * LSEQ * DHD;

    float mx = -FLT_MAX, sm = 0.f;
    for (int s = 0; s < NSAMP; ++s) {
        const int ks = idxs[l * NSAMP + s];
        float v = q * Kb[(size_t)ks * DHD + lane];
#pragma unroll
        for (int off = 32; off; off >>= 1) v += __shfl_xor(v, off);
        mx = fmaxf(mx, v);
        sm += v;
    }
    if (lane == 0) M[wid] = mx - sm * (1.0f / LSEQ);
}

// ---------------------------------------------------------------------------
// K3: stable top-40 per (b,h): iterative argmax, tie -> smallest index
// (matches jax.lax.top_k). Only the SET matters downstream (scatter), but
// keep stability anyway. Builds per-row head bitmask + slot table.
// ---------------------------------------------------------------------------
__global__ __launch_bounds__(256) void topk_kernel(
    const float* __restrict__ M, int* __restrict__ topidx,
    unsigned* __restrict__ headmask, unsigned char* __restrict__ slot)
{
    const int bh = blockIdx.x;           // 0..31
    const int b = bh >> 3, h = bh & 7;
    __shared__ float vals[LSEQ];
    __shared__ float rv[256];
    __shared__ int   ri[256];

    for (int i = threadIdx.x; i < LSEQ; i += 256) vals[i] = M[bh * LSEQ + i];
    __syncthreads();

    for (int t = 0; t < NTOP; ++t) {
        float bestv = -FLT_MAX; int besti = LSEQ;
        for (int i = threadIdx.x; i < LSEQ; i += 256) {
            const float v = vals[i];
            if (v > bestv) { bestv = v; besti = i; }   // ascending i: smallest on tie
        }
        rv[threadIdx.x] = bestv; ri[threadIdx.x] = besti;
        __syncthreads();
        for (int s2 = 128; s2; s2 >>= 1) {
            if (threadIdx.x < s2) {
                const float ov = rv[threadIdx.x + s2]; const int oi = ri[threadIdx.x + s2];
                if (ov > rv[threadIdx.x] || (ov == rv[threadIdx.x] && oi < ri[threadIdx.x])) {
                    rv[threadIdx.x] = ov; ri[threadIdx.x] = oi;
                }
            }
            __syncthreads();
        }
        if (threadIdx.x == 0) {
            const int w = ri[0];
            topidx[bh * NTOP + t] = w;
            atomicOr(&headmask[b * LSEQ + w], 1u << h);
            slot[bh * LSEQ + w] = (unsigned char)t;
            vals[w] = -FLT_MAX;
        }
        __syncthreads();
    }
}

// ---------------------------------------------------------------------------
// K4: per-(b,h,d) mean of V over L_enc.
// ---------------------------------------------------------------------------
__global__ __launch_bounds__(256) void vmean_kernel(
    const float* __restrict__ Vt, float* __restrict__ Vmean)
{
    const int bh = blockIdx.x;
    const int d = threadIdx.x & 63, q = threadIdx.x >> 6;
    const float* base = Vt + (size_t)bh * LSEQ * DHD;
    float s = 0.f;
    for (int l = q * 512; l < (q + 1) * 512; ++l) s += base[(size_t)l * DHD + d];
    __shared__ float red[256];
    red[threadIdx.x] = s;
    __syncthreads();
    if (q == 0)
        Vmean[bh * DHD + d] =
            (red[d] + red[64 + d] + red[128 + d] + red[192 + d]) * (1.f / (float)LSEQ);
}

// ---------------------------------------------------------------------------
// K5: mean-row output per batch: mean_out[b] = concat_h(Vmean) @ Wo^T + bo.
// ---------------------------------------------------------------------------
__global__ __launch_bounds__(256) void meanout_kernel(
    const float* __restrict__ Vmean, const float* __restrict__ Wo,
    const float* __restrict__ bo, float* __restrict__ meanout)
{
    const int b = blockIdx.x;
    __shared__ float mc[DMODEL];
    for (int i = threadIdx.x; i < DMODEL; i += 256) mc[i] = Vmean[b * DMODEL + i];
    __syncthreads();
    for (int n = threadIdx.x; n < DMODEL; n += 256) {
        float acc = bo[n];
        const float* wr = Wo + (size_t)n * DMODEL;
        for (int k = 0; k < DMODEL; ++k) acc = fmaf(mc[k], wr[k], acc);
        meanout[b * DMODEL + n] = acc;
    }
}

// ---------------------------------------------------------------------------
// K6: full attention for the selected queries; writes delta = upd - Vmean.
// One block per (b,h,u).
// ---------------------------------------------------------------------------
__global__ __launch_bounds__(256) void attn_kernel(
    const float* __restrict__ Qt, const float* __restrict__ Kt,
    const float* __restrict__ Vt, const int* __restrict__ topidx,
    const float* __restrict__ Vmean, float* __restrict__ delta)
{
    const int gid = blockIdx.x;            // bh*NTOP + u
    const int bh = gid / NTOP;
    const int l = topidx[gid];

    __shared__ float q[DHD];
    __shared__ float p[LSEQ];
    __shared__ float red[256];

    if (threadIdx.x < DHD) q[threadIdx.x] = Qt[((size_t)bh * LSEQ + l) * DHD + threadIdx.x];
    __syncthreads();

    const float* Kb = Kt + (size_t)bh * LSEQ * DHD;
    float lmax = -FLT_MAX;
    for (int kk = threadIdx.x; kk < LSEQ; kk += 256) {
        const float4* kr = reinterpret_cast<const float4*>(Kb + (size_t)kk * DHD);
        float acc = 0.f;
#pragma unroll
        for (int j = 0; j < 16; ++j) {
            const float4 kv = kr[j];
            acc += q[j * 4 + 0] * kv.x + q[j * 4 + 1] * kv.y +
                   q[j * 4 + 2] * kv.z + q[j * 4 + 3] * kv.w;
        }
        acc *= QK_SCALE;
        p[kk] = acc;
        lmax = fmaxf(lmax, acc);
    }
    red[threadIdx.x] = lmax;
    __syncthreads();
    for (int s = 128; s; s >>= 1) {
        if (threadIdx.x < s) red[threadIdx.x] = fmaxf(red[threadIdx.x], red[threadIdx.x + s]);
        __syncthreads();
    }
    const float mx = red[0];
    __syncthreads();

    float lsum = 0.f;
    for (int kk = threadIdx.x; kk < LSEQ; kk += 256) {
        const float e = expf(p[kk] - mx);
        p[kk] = e;
        lsum += e;
    }
    red[threadIdx.x] = lsum;
    __syncthreads();
    for (int s = 128; s; s >>= 1) {
        if (threadIdx.x < s) red[threadIdx.x] += red[threadIdx.x + s];
        __syncthreads();
    }
    const float inv = 1.0f / red[0];
    __syncthreads();

    const int d = threadIdx.x & 63, qq = threadIdx.x >> 6;
    const float* Vb = Vt + (size_t)bh * LSEQ * DHD;
    float acc = 0.f;
    for (int kk = qq * 512; kk < (qq + 1) * 512; ++kk)
        acc += p[kk] * Vb[(size_t)kk * DHD + d];
    red[threadIdx.x] = acc;
    __syncthreads();
    if (qq == 0) {
        const float upd = (red[d] + red[64 + d] + red[128 + d] + red[192 + d]) * inv;
        delta[(size_t)gid * DHD + d] = upd - Vmean[bh * DHD + d];
    }
}

// ---------------------------------------------------------------------------
// K7: final output rows: out[b,l,:] = mean_out[b] + sum_{h in mask} delta.Wo_h^T
// One block per (b,l) row; writes fp32.
// ---------------------------------------------------------------------------
__global__ __launch_bounds__(256) void out_kernel(
    const float* __restrict__ meanout, const unsigned* __restrict__ headmask,
    const unsigned char* __restrict__ slot, const float* __restrict__ delta,
    const float* __restrict__ Wo, float* __restrict__ out)
{
    const int rowg = blockIdx.x;           // b*LSEQ + l
    const int b = rowg >> 11, lloc = rowg & (LSEQ - 1);
    const unsigned mask = headmask[rowg];

    __shared__ float dl[NH][DHD];
    for (int h = 0; h < NH; ++h) {
        if ((mask >> h) & 1) {
            if (threadIdx.x < DHD) {
                const int bh = b * NH + h;
                const int u = slot[bh * LSEQ + lloc];
                dl[h][threadIdx.x] = delta[((size_t)bh * NTOP + u) * DHD + threadIdx.x];
            }
        }
    }
    __syncthreads();

#pragma unroll
    for (int i = 0; i < 2; ++i) {
        const int n = threadIdx.x + i * 256;
        float val = meanout[b * DMODEL + n];
        unsigned mm = mask;
        while (mm) {
            const int h = __ffs(mm) - 1;
            mm &= mm - 1;
            const float* wr = Wo + (size_t)n * DMODEL + h * DHD;
            float a = 0.f;
#pragma unroll
            for (int dd = 0; dd < DHD; ++dd) a = fmaf(dl[h][dd], wr[dd], a);
            val += a;
        }
        out[(size_t)rowg * DMODEL + n] = val;
    }
}

// ---------------------------------------------------------------------------
extern "C" void kernel_launch(void* const* d_in, const int* in_sizes, int n_in,
                              void* d_out, int out_size, void* d_ws, size_t ws_size,
                              hipStream_t stream)
{
    (void)in_sizes; (void)n_in; (void)out_size; (void)ws_size;
    const float* x     = (const float*)d_in[0];
    const float* ctxin = (const float*)d_in[1];
    const float* Wq    = (const float*)d_in[2];
    const float* bq    = (const float*)d_in[3];
    const float* Wk    = (const float*)d_in[4];
    const float* bk    = (const float*)d_in[5];
    const float* Wv    = (const float*)d_in[6];
    const float* bv    = (const float*)d_in[7];
    const float* Wo    = (const float*)d_in[8];
    const float* bo    = (const float*)d_in[9];
    const int*   idxs  = (const int*)d_in[10];
    float* out = (float*)d_out;

    char* ws = (char*)d_ws;
    size_t off = 0;
    auto alloc = [&](size_t bytes) -> void* {
        void* p = ws + off;
        off += (bytes + 255) & ~(size_t)255;
        return p;
    };

    const size_t qkv_bytes = (size_t)BATCH * NH * LSEQ * DHD * sizeof(float);
    float*         Qt       = (float*)alloc(qkv_bytes);
    float*         Kt       = (float*)alloc(qkv_bytes);
    float*         Vt       = (float*)alloc(qkv_bytes);
    float*         Mbuf     = (float*)alloc((size_t)BATCH * NH * LSEQ * sizeof(float));
    float*         Vmean    = (float*)alloc((size_t)BATCH * NH * DHD * sizeof(float));
    float*         meanout  = (float*)alloc((size_t)BATCH * DMODEL * sizeof(float));
    float*         delta    = (float*)alloc((size_t)BATCH * NH * NTOP * DHD * sizeof(float));
    int*           topidx   = (int*)alloc((size_t)BATCH * NH * NTOP * sizeof(int));
    unsigned*      headmask = (unsigned*)alloc((size_t)BATCH * LSEQ * sizeof(unsigned));
    unsigned char* slot     = (unsigned char*)alloc((size_t)BATCH * NH * LSEQ);

    qkv_gemm_f32<<<dim3(8192 / 128, DMODEL / 128, 3), 256, 0, stream>>>(
        x, ctxin, Wq, bq, Wk, bk, Wv, bv, Qt, Kt, Vt);

    score_kernel<<<(BATCH * NH * LSEQ) / 4, 256, 0, stream>>>(Qt, Kt, idxs, Mbuf);

    hipMemsetAsync(headmask, 0, (size_t)BATCH * LSEQ * sizeof(unsigned), stream);

    topk_kernel<<<BATCH * NH, 256, 0, stream>>>(Mbuf, topidx, headmask, slot);

    vmean_kernel<<<BATCH * NH, 256, 0, stream>>>(Vt, Vmean);

    meanout_kernel<<<BATCH, 256, 0, stream>>>(Vmean, Wo, bo, meanout);

    attn_kernel<<<BATCH * NH * NTOP, 256, 0, stream>>>(Qt, Kt, Vt, topidx, Vmean, delta);

    out_kernel<<<BATCH * LSEQ, 256, 0, stream>>>(meanout, headmask, slot, delta, Wo, out);
}

// Round 3
// 480.319 us; speedup vs baseline: 2.0032x; 2.0032x over previous
//
#include <hip/hip_runtime.h>
#include <float.h>

#define BATCH 4
#define LSEQ  2048
#define DMODEL 512
#define NH    8
#define DHD   64
#define NSAMP 40
#define NTOP  40
#define NCHUNK 32
#define TK    64                 // keys per attn chunk
#define QK_SCALE 0.125f          // 1/sqrt(64)

// ---------------------------------------------------------------------------
// K1: fp32 QKV GEMM (vector ALU — no fp32 MFMA on CDNA4; M-selection needs
// fp32-exact Q/K).  C = A @ W^T + b.  Tile 128x128, KSTEP=32, 8x8 micro-tile.
// ---------------------------------------------------------------------------
#define KSTEP 32

__global__ __launch_bounds__(256) void qkv_gemm_f32(
    const float* __restrict__ x, const float* __restrict__ ctxin,
    const float* __restrict__ Wq, const float* __restrict__ bq,
    const float* __restrict__ Wk, const float* __restrict__ bk,
    const float* __restrict__ Wv, const float* __restrict__ bv,
    float* __restrict__ Qt, float* __restrict__ Kt, float* __restrict__ Vt)
{
    const int z = blockIdx.z;
    const float* __restrict__ A    = (z == 0) ? x  : ctxin;
    const float* __restrict__ W    = (z == 0) ? Wq : (z == 1 ? Wk : Wv);
    const float* __restrict__ bias = (z == 0) ? bq : (z == 1 ? bk : bv);
    float*       __restrict__ Out  = (z == 0) ? Qt : (z == 1 ? Kt : Vt);

    __shared__ float As[KSTEP][128 + 4];   // [k][m]
    __shared__ float Ws[KSTEP][128 + 4];   // [k][n]

    const int tid = threadIdx.x;
    const int tn  = tid & 15;
    const int tm  = tid >> 4;
    const int m0  = blockIdx.x * 128;
    const int n0  = blockIdx.y * 128;

    const int srow = tid >> 3;
    const int sc4  = tid & 7;

    float acc[8][8] = {};

    for (int k0 = 0; k0 < DMODEL; k0 += KSTEP) {
        __syncthreads();
#pragma unroll
        for (int rr = 0; rr < 4; ++rr) {
            const int r = srow + rr * 32;
            const float4 av = *reinterpret_cast<const float4*>(
                A + (size_t)(m0 + r) * DMODEL + k0 + sc4 * 4);
            const float4 wv = *reinterpret_cast<const float4*>(
                W + (size_t)(n0 + r) * DMODEL + k0 + sc4 * 4);
            As[sc4 * 4 + 0][r] = av.x; As[sc4 * 4 + 1][r] = av.y;
            As[sc4 * 4 + 2][r] = av.z; As[sc4 * 4 + 3][r] = av.w;
            Ws[sc4 * 4 + 0][r] = wv.x; Ws[sc4 * 4 + 1][r] = wv.y;
            Ws[sc4 * 4 + 2][r] = wv.z; Ws[sc4 * 4 + 3][r] = wv.w;
        }
        __syncthreads();
#pragma unroll
        for (int kk = 0; kk < KSTEP; ++kk) {
            float a[8], b[8];
            *reinterpret_cast<float4*>(&a[0]) =
                *reinterpret_cast<const float4*>(&As[kk][tm * 8]);
            *reinterpret_cast<float4*>(&a[4]) =
                *reinterpret_cast<const float4*>(&As[kk][tm * 8 + 4]);
            *reinterpret_cast<float4*>(&b[0]) =
                *reinterpret_cast<const float4*>(&Ws[kk][tn * 8]);
            *reinterpret_cast<float4*>(&b[4]) =
                *reinterpret_cast<const float4*>(&Ws[kk][tn * 8 + 4]);
#pragma unroll
            for (int i = 0; i < 8; ++i)
#pragma unroll
                for (int j = 0; j < 8; ++j)
                    acc[i][j] = fmaf(a[i], b[j], acc[i][j]);
        }
    }

    const int mbase = m0 + tm * 8;
    const int nbase = n0 + tn * 8;
#pragma unroll
    for (int i = 0; i < 8; ++i) {
        const int m = mbase + i;
        const int b = m >> 11, l = m & (LSEQ - 1);
#pragma unroll
        for (int j = 0; j < 8; ++j) {
            const int n = nbase + j;
            const int h = n >> 6, d = n & 63;
            Out[(((size_t)(b * NH + h) * LSEQ) + l) * DHD + d] = acc[i][j] + bias[n];
        }
    }
}

// ---------------------------------------------------------------------------
// K2: sampled sparsity measure. Lane-per-sample (lanes 0..39 active for the
// dot), single butterfly pair at the end. XCD-chunked block swizzle keeps each
// (b,h)'s 2MB K gather set resident in one XCD's L2.
// ---------------------------------------------------------------------------
__global__ __launch_bounds__(256) void score_kernel(
    const float* __restrict__ Qt, const float* __restrict__ Kt,
    const int* __restrict__ idxs, float* __restrict__ M)
{
    const int flat = blockIdx.x;             // 16384 blocks
    const int xcd  = flat & 7;
    const int slot = flat >> 3;              // 0..2047
    const int bh   = xcd * 4 + (slot >> 9);  // 4 bh per XCD
    const int w    = threadIdx.x >> 6;
    const int lane = threadIdx.x & 63;
    const int l    = (slot & 511) * 4 + w;

    __shared__ float qs[4][DHD];
    qs[w][lane] = Qt[((size_t)bh * LSEQ + l) * DHD + lane];
    __syncthreads();

    float acc = 0.f;
    if (lane < NSAMP) {
        const int ks = idxs[l * NSAMP + lane];
        const float4* kr = reinterpret_cast<const float4*>(
            Kt + ((size_t)bh * LSEQ + ks) * DHD);
#pragma unroll
        for (int j = 0; j < 16; ++j) {
            const float4 kv = kr[j];
            acc += qs[w][j * 4 + 0] * kv.x + qs[w][j * 4 + 1] * kv.y +
                   qs[w][j * 4 + 2] * kv.z + qs[w][j * 4 + 3] * kv.w;
        }
    }
    float vmax = (lane < NSAMP) ? acc : -FLT_MAX;
    float vsum = (lane < NSAMP) ? acc : 0.f;
#pragma unroll
    for (int off = 32; off; off >>= 1) {
        vmax = fmaxf(vmax, __shfl_xor(vmax, off));
        vsum += __shfl_xor(vsum, off);
    }
    if (lane == 0) M[(size_t)bh * LSEQ + l] = vmax - vsum * (1.0f / LSEQ);
}

// ---------------------------------------------------------------------------
// K3: stable top-40 per (b,h); wave-shuffle argmax, 2 barriers/iter.
// ---------------------------------------------------------------------------
__global__ __launch_bounds__(256) void topk_kernel(
    const float* __restrict__ M, int* __restrict__ topidx,
    unsigned* __restrict__ headmask, unsigned char* __restrict__ slot)
{
    const int bh = blockIdx.x;
    const int b = bh >> 3, h = bh & 7;
    const int w = threadIdx.x >> 6, lane = threadIdx.x & 63;
    __shared__ float vals[LSEQ];
    __shared__ float rv[4];
    __shared__ int   ri[4];

    for (int i = threadIdx.x; i < LSEQ; i += 256) vals[i] = M[bh * LSEQ + i];
    __syncthreads();

    for (int t = 0; t < NTOP; ++t) {
        float bv = -FLT_MAX; int bi = LSEQ;
        for (int i = threadIdx.x; i < LSEQ; i += 256) {
            const float v = vals[i];
            if (v > bv) { bv = v; bi = i; }          // ascending: smallest on tie
        }
#pragma unroll
        for (int off = 32; off; off >>= 1) {
            const float ov = __shfl_xor(bv, off);
            const int   oi = __shfl_xor(bi, off);
            if (ov > bv || (ov == bv && oi < bi)) { bv = ov; bi = oi; }
        }
        if (lane == 0) { rv[w] = bv; ri[w] = bi; }
        __syncthreads();
        if (threadIdx.x == 0) {
            float fv = rv[0]; int fi = ri[0];
#pragma unroll
            for (int k = 1; k < 4; ++k)
                if (rv[k] > fv || (rv[k] == fv && ri[k] < fi)) { fv = rv[k]; fi = ri[k]; }
            topidx[bh * NTOP + t] = fi;
            atomicOr(&headmask[b * LSEQ + fi], 1u << h);
            slot[bh * LSEQ + fi] = (unsigned char)t;
            vals[fi] = -FLT_MAX;
        }
        __syncthreads();
    }
}

// ---------------------------------------------------------------------------
// K4: V column sums (raw, scaled by consumers). 256 blocks + atomicAdd.
// ---------------------------------------------------------------------------
__global__ __launch_bounds__(256) void vmean_kernel(
    const float* __restrict__ Vt, float* __restrict__ VmeanRaw)
{
    const int bh = blockIdx.x;
    const int d = threadIdx.x & 63, part = threadIdx.x >> 6;
    const int l0 = blockIdx.y * 256 + part * 64;
    const float* base = Vt + (size_t)bh * LSEQ * DHD;
    float s = 0.f;
    for (int i = 0; i < 64; ++i) s += base[(size_t)(l0 + i) * DHD + d];
    __shared__ float red[256];
    red[threadIdx.x] = s;
    __syncthreads();
    if (part == 0)
        atomicAdd(&VmeanRaw[bh * DHD + d],
                  red[d] + red[64 + d] + red[128 + d] + red[192 + d]);
}

// ---------------------------------------------------------------------------
// K5: mean-row output per batch.
// ---------------------------------------------------------------------------
__global__ __launch_bounds__(256) void meanout_kernel(
    const float* __restrict__ VmeanRaw, const float* __restrict__ Wo,
    const float* __restrict__ bo, float* __restrict__ meanout)
{
    const int b = blockIdx.x;
    __shared__ float mc[DMODEL];
    for (int i = threadIdx.x; i < DMODEL; i += 256)
        mc[i] = VmeanRaw[b * DMODEL + i] * (1.0f / (float)LSEQ);
    __syncthreads();
    for (int n = threadIdx.x; n < DMODEL; n += 256) {
        float acc = bo[n];
        const float* wr = Wo + (size_t)n * DMODEL;
        for (int k = 0; k < DMODEL; ++k) acc = fmaf(mc[k], wr[k], acc);
        meanout[b * DMODEL + n] = acc;
    }
}

// ---------------------------------------------------------------------------
// K6a: flash split-K attention partials. Block = (bh, key-chunk of 64).
// K/V read ONCE total. exp without max-subtraction (scores O(+-8), fp32 exp
// overflows only past 88) — mathematically identical to softmax-with-max.
// ---------------------------------------------------------------------------
__global__ __launch_bounds__(256) void attn_partial(
    const float* __restrict__ Qt, const float* __restrict__ Kt,
    const float* __restrict__ Vt, const int* __restrict__ topidx,
    float* __restrict__ psums, float* __restrict__ pacc)
{
    const int bh = blockIdx.x;
    const int c  = blockIdx.y;
    const int kbase = c * TK;
    const int tid = threadIdx.x;

    __shared__ float Qs[NTOP][DHD];      // 10240 B
    __shared__ float Ks[TK][68];         // 17408 B (bank-balanced pad)
    __shared__ float Vs[TK][68];         // 17408 B
    __shared__ float Sc[TK][52];         // 13312 B  [k][q], 52: b128-aligned pad

    // --- stage Q (gathered rows), K, V chunks ---
    for (int i = tid; i < NTOP * DHD; i += 256) {
        const int q = i >> 6, d = i & 63;
        const int row = topidx[bh * NTOP + q];
        Qs[q][d] = Qt[((size_t)bh * LSEQ + row) * DHD + d];
    }
    {
        const int r0 = tid >> 4, c4 = tid & 15;
#pragma unroll
        for (int rr = 0; rr < 4; ++rr) {
            const int r = r0 + rr * 16;
            const size_t g = ((size_t)bh * LSEQ + kbase + r) * DHD + c4 * 4;
            *reinterpret_cast<float4*>(&Ks[r][c4 * 4]) =
                *reinterpret_cast<const float4*>(Kt + g);
            *reinterpret_cast<float4*>(&Vs[r][c4 * 4]) =
                *reinterpret_cast<const float4*>(Vt + g);
        }
    }
    __syncthreads();

    // --- scores: 40q x 64k, thread -> (q = it*4+wave, k = lane) ---
    {
        const int k = tid & 63;
#pragma unroll
        for (int it = 0; it < 10; ++it) {
            const int q = it * 4 + (tid >> 6);
            float acc = 0.f;
#pragma unroll
            for (int j = 0; j < 16; ++j) {
                const float4 kv = *reinterpret_cast<const float4*>(&Ks[k][j * 4]);
                const float4 qv = *reinterpret_cast<const float4*>(&Qs[q][j * 4]);
                acc += qv.x * kv.x + qv.y * kv.y + qv.z * kv.z + qv.w * kv.w;
            }
            Sc[k][q] = acc * QK_SCALE;
        }
    }
    __syncthreads();

    // --- exp + per-chunk partial sum (wave w handles q = w*10..w*10+9) ---
    {
        const int w = tid >> 6, lane = tid & 63;
#pragma unroll
        for (int j = 0; j < 10; ++j) {
            const int q = w * 10 + j;
            const float e = __expf(Sc[lane][q]);
            float s = e;
#pragma unroll
            for (int off = 32; off; off >>= 1) s += __shfl_xor(s, off);
            Sc[lane][q] = e;
            if (lane == 0) psums[((size_t)bh * NCHUNK + c) * NTOP + q] = s;
        }
    }
    __syncthreads();

    // --- partial PV: thread -> (d = tid&63, q-group of 12) ---
    {
        const int d = tid & 63, g = tid >> 6;
        const int q0 = g * 12;
        const int nq = (g < 3) ? 12 : 4;
        float acc[12] = {};
        for (int k = 0; k < TK; ++k) {
            const float v = Vs[k][d];
            const float4 s0 = *reinterpret_cast<const float4*>(&Sc[k][q0]);
            acc[0] = fmaf(s0.x, v, acc[0]); acc[1] = fmaf(s0.y, v, acc[1]);
            acc[2] = fmaf(s0.z, v, acc[2]); acc[3] = fmaf(s0.w, v, acc[3]);
            if (g < 3) {
                const float4 s1 = *reinterpret_cast<const float4*>(&Sc[k][q0 + 4]);
                const float4 s2 = *reinterpret_cast<const float4*>(&Sc[k][q0 + 8]);
                acc[4] = fmaf(s1.x, v, acc[4]); acc[5]  = fmaf(s1.y, v, acc[5]);
                acc[6] = fmaf(s1.z, v, acc[6]); acc[7]  = fmaf(s1.w, v, acc[7]);
                acc[8] = fmaf(s2.x, v, acc[8]); acc[9]  = fmaf(s2.y, v, acc[9]);
                acc[10] = fmaf(s2.z, v, acc[10]); acc[11] = fmaf(s2.w, v, acc[11]);
            }
        }
#pragma unroll
        for (int j = 0; j < 12; ++j)
            if (j < nq)
                pacc[(((size_t)bh * NCHUNK + c) * NTOP + q0 + j) * DHD + d] = acc[j];
    }
}

// ---------------------------------------------------------------------------
// K6b: combine partials -> delta = upd - Vmean. One block per bh.
// ---------------------------------------------------------------------------
__global__ __launch_bounds__(256) void attn_combine(
    const float* __restrict__ psums, const float* __restrict__ pacc,
    const float* __restrict__ VmeanRaw, float* __restrict__ delta)
{
    const int bh = blockIdx.x;
    __shared__ float winv[NTOP];
    if (threadIdx.x < NTOP) {
        float s = 0.f;
        for (int c = 0; c < NCHUNK; ++c)
            s += psums[((size_t)bh * NCHUNK + c) * NTOP + threadIdx.x];
        winv[threadIdx.x] = 1.0f / s;
    }
    __syncthreads();
    const int d = threadIdx.x & 63, g = threadIdx.x >> 6;
    const float vm = VmeanRaw[bh * DHD + d] * (1.0f / (float)LSEQ);
    for (int q = g; q < NTOP; q += 4) {
        float a = 0.f;
        for (int c = 0; c < NCHUNK; ++c)
            a += pacc[(((size_t)bh * NCHUNK + c) * NTOP + q) * DHD + d];
        delta[((size_t)bh * NTOP + q) * DHD + d] = a * winv[q] - vm;
    }
}

// ---------------------------------------------------------------------------
// K7: final output rows.
// ---------------------------------------------------------------------------
__global__ __launch_bounds__(256) void out_kernel(
    const float* __restrict__ meanout, const unsigned* __restrict__ headmask,
    const unsigned char* __restrict__ slot, const float* __restrict__ delta,
    const float* __restrict__ Wo, float* __restrict__ out)
{
    const int rowg = blockIdx.x;
    const int b = rowg >> 11, lloc = rowg & (LSEQ - 1);
    const unsigned mask = headmask[rowg];

    __shared__ float dl[NH][DHD];
    for (int h = 0; h < NH; ++h) {
        if ((mask >> h) & 1) {
            if (threadIdx.x < DHD) {
                const int bh = b * NH + h;
                const int u = slot[bh * LSEQ + lloc];
                dl[h][threadIdx.x] = delta[((size_t)bh * NTOP + u) * DHD + threadIdx.x];
            }
        }
    }
    __syncthreads();

#pragma unroll
    for (int i = 0; i < 2; ++i) {
        const int n = threadIdx.x + i * 256;
        float val = meanout[b * DMODEL + n];
        unsigned mm = mask;
        while (mm) {
            const int h = __ffs(mm) - 1;
            mm &= mm - 1;
            const float* wr = Wo + (size_t)n * DMODEL + h * DHD;
            float a = 0.f;
#pragma unroll
            for (int dd = 0; dd < DHD; ++dd) a = fmaf(dl[h][dd], wr[dd], a);
            val += a;
        }
        out[(size_t)rowg * DMODEL + n] = val;
    }
}

// ---------------------------------------------------------------------------
extern "C" void kernel_launch(void* const* d_in, const int* in_sizes, int n_in,
                              void* d_out, int out_size, void* d_ws, size_t ws_size,
                              hipStream_t stream)
{
    (void)in_sizes; (void)n_in; (void)out_size; (void)ws_size;
    const float* x     = (const float*)d_in[0];
    const float* ctxin = (const float*)d_in[1];
    const float* Wq    = (const float*)d_in[2];
    const float* bq    = (const float*)d_in[3];
    const float* Wk    = (const float*)d_in[4];
    const float* bk    = (const float*)d_in[5];
    const float* Wv    = (const float*)d_in[6];
    const float* bv    = (const float*)d_in[7];
    const float* Wo    = (const float*)d_in[8];
    const float* bo    = (const float*)d_in[9];
    const int*   idxs  = (const int*)d_in[10];
    float* out = (float*)d_out;

    char* ws = (char*)d_ws;
    size_t off = 0;
    auto alloc = [&](size_t bytes) -> void* {
        void* p = ws + off;
        off += (bytes + 255) & ~(size_t)255;
        return p;
    };

    const size_t qkv_bytes = (size_t)BATCH * NH * LSEQ * DHD * sizeof(float);
    float*         Qt       = (float*)alloc(qkv_bytes);
    float*         Kt       = (float*)alloc(qkv_bytes);
    float*         Vt       = (float*)alloc(qkv_bytes);
    float*         Mbuf     = (float*)alloc((size_t)BATCH * NH * LSEQ * sizeof(float));
    float*         VmeanRaw = (float*)alloc((size_t)BATCH * NH * DHD * sizeof(float));
    float*         meanout  = (float*)alloc((size_t)BATCH * DMODEL * sizeof(float));
    float*         delta    = (float*)alloc((size_t)BATCH * NH * NTOP * DHD * sizeof(float));
    int*           topidx   = (int*)alloc((size_t)BATCH * NH * NTOP * sizeof(int));
    unsigned*      headmask = (unsigned*)alloc((size_t)BATCH * LSEQ * sizeof(unsigned));
    unsigned char* slot     = (unsigned char*)alloc((size_t)BATCH * NH * LSEQ);
    float*         psums    = (float*)alloc((size_t)BATCH * NH * NCHUNK * NTOP * sizeof(float));
    float*         pacc     = (float*)alloc((size_t)BATCH * NH * NCHUNK * NTOP * DHD * sizeof(float));

    qkv_gemm_f32<<<dim3(8192 / 128, DMODEL / 128, 3), 256, 0, stream>>>(
        x, ctxin, Wq, bq, Wk, bk, Wv, bv, Qt, Kt, Vt);

    score_kernel<<<(BATCH * NH * LSEQ) / 4, 256, 0, stream>>>(Qt, Kt, idxs, Mbuf);

    hipMemsetAsync(headmask, 0, (size_t)BATCH * LSEQ * sizeof(unsigned), stream);
    hipMemsetAsync(VmeanRaw, 0, (size_t)BATCH * NH * DHD * sizeof(float), stream);

    topk_kernel<<<BATCH * NH, 256, 0, stream>>>(Mbuf, topidx, headmask, slot);

    vmean_kernel<<<dim3(BATCH * NH, LSEQ / 256), 256, 0, stream>>>(Vt, VmeanRaw);

    meanout_kernel<<<BATCH, 256, 0, stream>>>(VmeanRaw, Wo, bo, meanout);

    attn_partial<<<dim3(BATCH * NH, NCHUNK), 256, 0, stream>>>(
        Qt, Kt, Vt, topidx, psums, pacc);

    attn_combine<<<BATCH * NH, 256, 0, stream>>>(psums, pacc, VmeanRaw, delta);

    out_kernel<<<BATCH * LSEQ, 256, 0, stream>>>(meanout, headmask, slot, delta, Wo, out);
}

// Round 4
// 460.193 us; speedup vs baseline: 2.0908x; 1.0437x over previous
//
#include <hip/hip_runtime.h>
#include <float.h>

#define BATCH 4
#define LSEQ  2048
#define DMODEL 512
#define NH    8
#define DHD   64
#define NSAMP 40
#define NTOP  40
#define NCHUNK 32
#define TK    64                 // keys per attn chunk
#define QK_SCALE 0.125f          // 1/sqrt(64)

// ---------------------------------------------------------------------------
// K1: fp32 QKV GEMM (vector ALU — no fp32 MFMA on CDNA4; M-selection needs
// fp32-exact Q/K).  C = A @ W^T + b.  Tile 128x128, KSTEP=32, 8x8 micro-tile.
// v2: async-stage (global->reg early, reg->LDS late), bank-conflict-free
// fragment layout (n split 4+4 at stride 64), float4 epilogue.
// ---------------------------------------------------------------------------
#define KSTEP 32

__global__ __launch_bounds__(256) void qkv_gemm_f32(
    const float* __restrict__ x, const float* __restrict__ ctxin,
    const float* __restrict__ Wq, const float* __restrict__ bq,
    const float* __restrict__ Wk, const float* __restrict__ bk,
    const float* __restrict__ Wv, const float* __restrict__ bv,
    float* __restrict__ Qt, float* __restrict__ Kt, float* __restrict__ Vt)
{
    const int z = blockIdx.z;
    const float* __restrict__ A    = (z == 0) ? x  : ctxin;
    const float* __restrict__ W    = (z == 0) ? Wq : (z == 1 ? Wk : Wv);
    const float* __restrict__ bias = (z == 0) ? bq : (z == 1 ? bk : bv);
    float*       __restrict__ Out  = (z == 0) ? Qt : (z == 1 ? Kt : Vt);

    __shared__ float As[KSTEP][128 + 4];   // [k][m]
    __shared__ float Ws[KSTEP][128 + 4];   // [k][n]

    const int tid = threadIdx.x;
    const int tn  = tid & 15;
    const int tm  = tid >> 4;
    const int m0  = blockIdx.x * 128;
    const int n0  = blockIdx.y * 128;

    const int srow = tid >> 3;           // 0..31
    const int sc4  = tid & 7;            // 0..7

    float acc[8][8] = {};
    float4 ar[4], wr[4];

    // prologue: issue tile-0 loads
#pragma unroll
    for (int rr = 0; rr < 4; ++rr) {
        const int r = srow + rr * 32;
        ar[rr] = *reinterpret_cast<const float4*>(A + (size_t)(m0 + r) * DMODEL + sc4 * 4);
        wr[rr] = *reinterpret_cast<const float4*>(W + (size_t)(n0 + r) * DMODEL + sc4 * 4);
    }

    for (int k0 = 0; k0 < DMODEL; k0 += KSTEP) {
        // write staged regs -> LDS (transposed)
#pragma unroll
        for (int rr = 0; rr < 4; ++rr) {
            const int r = srow + rr * 32;
            As[sc4 * 4 + 0][r] = ar[rr].x; As[sc4 * 4 + 1][r] = ar[rr].y;
            As[sc4 * 4 + 2][r] = ar[rr].z; As[sc4 * 4 + 3][r] = ar[rr].w;
            Ws[sc4 * 4 + 0][r] = wr[rr].x; Ws[sc4 * 4 + 1][r] = wr[rr].y;
            Ws[sc4 * 4 + 2][r] = wr[rr].z; Ws[sc4 * 4 + 3][r] = wr[rr].w;
        }
        __syncthreads();

        // issue next tile's global loads (latency hides under compute)
        if (k0 + KSTEP < DMODEL) {
#pragma unroll
            for (int rr = 0; rr < 4; ++rr) {
                const int r = srow + rr * 32;
                ar[rr] = *reinterpret_cast<const float4*>(
                    A + (size_t)(m0 + r) * DMODEL + k0 + KSTEP + sc4 * 4);
                wr[rr] = *reinterpret_cast<const float4*>(
                    W + (size_t)(n0 + r) * DMODEL + k0 + KSTEP + sc4 * 4);
            }
        }

#pragma unroll
        for (int kk = 0; kk < KSTEP; ++kk) {
            float a[8], b[8];
            *reinterpret_cast<float4*>(&a[0]) =
                *reinterpret_cast<const float4*>(&As[kk][tm * 8]);
            *reinterpret_cast<float4*>(&a[4]) =
                *reinterpret_cast<const float4*>(&As[kk][tm * 8 + 4]);
            *reinterpret_cast<float4*>(&b[0]) =
                *reinterpret_cast<const float4*>(&Ws[kk][tn * 4]);        // 2-way, free
            *reinterpret_cast<float4*>(&b[4]) =
                *reinterpret_cast<const float4*>(&Ws[kk][64 + tn * 4]);   // 2-way, free
#pragma unroll
            for (int i = 0; i < 8; ++i)
#pragma unroll
                for (int j = 0; j < 8; ++j)
                    acc[i][j] = fmaf(a[i], b[j], acc[i][j]);
        }
        __syncthreads();
    }

    // epilogue: float4 stores. n columns: {n0+tn*4+0..3} and {n0+64+tn*4+0..3}
    const float4 bias_a = *reinterpret_cast<const float4*>(bias + n0 + tn * 4);
    const float4 bias_b = *reinterpret_cast<const float4*>(bias + n0 + 64 + tn * 4);
#pragma unroll
    for (int i = 0; i < 8; ++i) {
        const int m = m0 + tm * 8 + i;
        const int b = m >> 11, l = m & (LSEQ - 1);
#pragma unroll
        for (int jg = 0; jg < 2; ++jg) {
            const int nb = n0 + jg * 64 + tn * 4;
            const int h = nb >> 6, d = nb & 63;
            const float4 bi = jg ? bias_b : bias_a;
            float4 o;
            o.x = acc[i][jg * 4 + 0] + bi.x;
            o.y = acc[i][jg * 4 + 1] + bi.y;
            o.z = acc[i][jg * 4 + 2] + bi.z;
            o.w = acc[i][jg * 4 + 3] + bi.w;
            *reinterpret_cast<float4*>(
                Out + (((size_t)(b * NH + h) * LSEQ) + l) * DHD + d) = o;
        }
    }
}

// ---------------------------------------------------------------------------
// K2: sampled sparsity measure. Lane-per-sample; wave-local Q staging (no
// block barrier). XCD-chunked swizzle keeps each (b,h)'s K set L2-resident.
// ---------------------------------------------------------------------------
__global__ __launch_bounds__(256) void score_kernel(
    const float* __restrict__ Qt, const float* __restrict__ Kt,
    const int* __restrict__ idxs, float* __restrict__ M)
{
    const int flat = blockIdx.x;             // 16384 blocks
    const int xcd  = flat & 7;
    const int slot = flat >> 3;              // 0..2047
    const int bh   = xcd * 4 + (slot >> 9);  // 4 bh per XCD
    const int w    = threadIdx.x >> 6;
    const int lane = threadIdx.x & 63;
    const int l    = (slot & 511) * 4 + w;

    __shared__ float qs[4][DHD];
    qs[w][lane] = Qt[((size_t)bh * LSEQ + l) * DHD + lane];  // wave-local RAW

    float acc = 0.f;
    if (lane < NSAMP) {
        const int ks = idxs[l * NSAMP + lane];
        const float4* kr = reinterpret_cast<const float4*>(
            Kt + ((size_t)bh * LSEQ + ks) * DHD);
#pragma unroll
        for (int j = 0; j < 16; ++j) {
            const float4 kv = kr[j];
            acc += qs[w][j * 4 + 0] * kv.x + qs[w][j * 4 + 1] * kv.y +
                   qs[w][j * 4 + 2] * kv.z + qs[w][j * 4 + 3] * kv.w;
        }
    }
    float vmax = (lane < NSAMP) ? acc : -FLT_MAX;
    float vsum = (lane < NSAMP) ? acc : 0.f;
#pragma unroll
    for (int off = 32; off; off >>= 1) {
        vmax = fmaxf(vmax, __shfl_xor(vmax, off));
        vsum += __shfl_xor(vsum, off);
    }
    if (lane == 0) M[(size_t)bh * LSEQ + l] = vmax - vsum * (1.0f / LSEQ);
}

// ---------------------------------------------------------------------------
// K3: stable top-40 per (b,h). v2: candidates in registers (8/thread);
// per iter: 7 reg-cmps + wave shuffle + 4-way merge + 2 barriers.
// ---------------------------------------------------------------------------
__global__ __launch_bounds__(256) void topk_kernel(
    const float* __restrict__ M, int* __restrict__ topidx,
    unsigned* __restrict__ headmask, unsigned char* __restrict__ slot)
{
    const int bh = blockIdx.x;
    const int b = bh >> 3, h = bh & 7;
    const int w = threadIdx.x >> 6, lane = threadIdx.x & 63;
    const int base = threadIdx.x * 8;

    float e[8];
    {
        const float4 v0 = *reinterpret_cast<const float4*>(M + (size_t)bh * LSEQ + base);
        const float4 v1 = *reinterpret_cast<const float4*>(M + (size_t)bh * LSEQ + base + 4);
        e[0] = v0.x; e[1] = v0.y; e[2] = v0.z; e[3] = v0.w;
        e[4] = v1.x; e[5] = v1.y; e[6] = v1.z; e[7] = v1.w;
    }

    __shared__ float rv[4];
    __shared__ int   ri[4];
    __shared__ int   winner;

    for (int t = 0; t < NTOP; ++t) {
        float bv = e[0]; int br = 0;
#pragma unroll
        for (int r = 1; r < 8; ++r)
            if (e[r] > bv) { bv = e[r]; br = r; }    // strict >: smallest r on tie
        int bi = base + br;
#pragma unroll
        for (int off = 32; off; off >>= 1) {
            const float ov = __shfl_xor(bv, off);
            const int   oi = __shfl_xor(bi, off);
            if (ov > bv || (ov == bv && oi < bi)) { bv = ov; bi = oi; }
        }
        if (lane == 0) { rv[w] = bv; ri[w] = bi; }
        __syncthreads();
        if (threadIdx.x == 0) {
            float fv = rv[0]; int fi = ri[0];
#pragma unroll
            for (int k = 1; k < 4; ++k)
                if (rv[k] > fv || (rv[k] == fv && ri[k] < fi)) { fv = rv[k]; fi = ri[k]; }
            topidx[bh * NTOP + t] = fi;
            atomicOr(&headmask[b * LSEQ + fi], 1u << h);
            slot[bh * LSEQ + fi] = (unsigned char)t;
            winner = fi;
        }
        __syncthreads();
        const int fi = winner;
        if ((fi >> 3) == threadIdx.x) e[fi & 7] = -FLT_MAX;
    }
}

// ---------------------------------------------------------------------------
// K4: V column sums (raw, scaled by consumers). 256 blocks + atomicAdd.
// ---------------------------------------------------------------------------
__global__ __launch_bounds__(256) void vmean_kernel(
    const float* __restrict__ Vt, float* __restrict__ VmeanRaw)
{
    const int bh = blockIdx.x;
    const int d = threadIdx.x & 63, part = threadIdx.x >> 6;
    const int l0 = blockIdx.y * 256 + part * 64;
    const float* base = Vt + (size_t)bh * LSEQ * DHD;
    float s = 0.f;
    for (int i = 0; i < 64; ++i) s += base[(size_t)(l0 + i) * DHD + d];
    __shared__ float red[256];
    red[threadIdx.x] = s;
    __syncthreads();
    if (part == 0)
        atomicAdd(&VmeanRaw[bh * DHD + d],
                  red[d] + red[64 + d] + red[128 + d] + red[192 + d]);
}

// ---------------------------------------------------------------------------
// K5: mean-row output per batch.
// ---------------------------------------------------------------------------
__global__ __launch_bounds__(256) void meanout_kernel(
    const float* __restrict__ VmeanRaw, const float* __restrict__ Wo,
    const float* __restrict__ bo, float* __restrict__ meanout)
{
    const int b = blockIdx.x;
    __shared__ float mc[DMODEL];
    for (int i = threadIdx.x; i < DMODEL; i += 256)
        mc[i] = VmeanRaw[b * DMODEL + i] * (1.0f / (float)LSEQ);
    __syncthreads();
    for (int n = threadIdx.x; n < DMODEL; n += 256) {
        float acc = bo[n];
        const float* wr = Wo + (size_t)n * DMODEL;
        for (int k = 0; k < DMODEL; ++k) acc = fmaf(mc[k], wr[k], acc);
        meanout[b * DMODEL + n] = acc;
    }
}

// ---------------------------------------------------------------------------
// K6a: flash split-K attention partials. Block = (bh, key-chunk of 64).
// K/V read ONCE total. exp without max-subtraction (scores O(+-8); fp32 exp
// overflows only past 88) — mathematically identical to softmax-with-max.
// ---------------------------------------------------------------------------
__global__ __launch_bounds__(256) void attn_partial(
    const float* __restrict__ Qt, const float* __restrict__ Kt,
    const float* __restrict__ Vt, const int* __restrict__ topidx,
    float* __restrict__ psums, float* __restrict__ pacc)
{
    const int bh = blockIdx.x;
    const int c  = blockIdx.y;
    const int kbase = c * TK;
    const int tid = threadIdx.x;

    __shared__ float Qs[NTOP][DHD];
    __shared__ float Ks[TK][68];
    __shared__ float Vs[TK][68];
    __shared__ float Sc[TK][52];

    for (int i = tid; i < NTOP * DHD; i += 256) {
        const int q = i >> 6, d = i & 63;
        const int row = topidx[bh * NTOP + q];
        Qs[q][d] = Qt[((size_t)bh * LSEQ + row) * DHD + d];
    }
    {
        const int r0 = tid >> 4, c4 = tid & 15;
#pragma unroll
        for (int rr = 0; rr < 4; ++rr) {
            const int r = r0 + rr * 16;
            const size_t g = ((size_t)bh * LSEQ + kbase + r) * DHD + c4 * 4;
            *reinterpret_cast<float4*>(&Ks[r][c4 * 4]) =
                *reinterpret_cast<const float4*>(Kt + g);
            *reinterpret_cast<float4*>(&Vs[r][c4 * 4]) =
                *reinterpret_cast<const float4*>(Vt + g);
        }
    }
    __syncthreads();

    {
        const int k = tid & 63;
#pragma unroll
        for (int it = 0; it < 10; ++it) {
            const int q = it * 4 + (tid >> 6);
            float acc = 0.f;
#pragma unroll
            for (int j = 0; j < 16; ++j) {
                const float4 kv = *reinterpret_cast<const float4*>(&Ks[k][j * 4]);
                const float4 qv = *reinterpret_cast<const float4*>(&Qs[q][j * 4]);
                acc += qv.x * kv.x + qv.y * kv.y + qv.z * kv.z + qv.w * kv.w;
            }
            Sc[k][q] = acc * QK_SCALE;
        }
    }
    __syncthreads();

    {
        const int w = tid >> 6, lane = tid & 63;
#pragma unroll
        for (int j = 0; j < 10; ++j) {
            const int q = w * 10 + j;
            const float ee = __expf(Sc[lane][q]);
            float s = ee;
#pragma unroll
            for (int off = 32; off; off >>= 1) s += __shfl_xor(s, off);
            Sc[lane][q] = ee;
            if (lane == 0) psums[((size_t)bh * NCHUNK + c) * NTOP + q] = s;
        }
    }
    __syncthreads();

    {
        const int d = tid & 63, g = tid >> 6;
        const int q0 = g * 12;
        const int nq = (g < 3) ? 12 : 4;
        float acc[12] = {};
        for (int k = 0; k < TK; ++k) {
            const float v = Vs[k][d];
            const float4 s0 = *reinterpret_cast<const float4*>(&Sc[k][q0]);
            acc[0] = fmaf(s0.x, v, acc[0]); acc[1] = fmaf(s0.y, v, acc[1]);
            acc[2] = fmaf(s0.z, v, acc[2]); acc[3] = fmaf(s0.w, v, acc[3]);
            if (g < 3) {
                const float4 s1 = *reinterpret_cast<const float4*>(&Sc[k][q0 + 4]);
                const float4 s2 = *reinterpret_cast<const float4*>(&Sc[k][q0 + 8]);
                acc[4] = fmaf(s1.x, v, acc[4]); acc[5]  = fmaf(s1.y, v, acc[5]);
                acc[6] = fmaf(s1.z, v, acc[6]); acc[7]  = fmaf(s1.w, v, acc[7]);
                acc[8] = fmaf(s2.x, v, acc[8]); acc[9]  = fmaf(s2.y, v, acc[9]);
                acc[10] = fmaf(s2.z, v, acc[10]); acc[11] = fmaf(s2.w, v, acc[11]);
            }
        }
#pragma unroll
        for (int j = 0; j < 12; ++j)
            if (j < nq)
                pacc[(((size_t)bh * NCHUNK + c) * NTOP + q0 + j) * DHD + d] = acc[j];
    }
}

// ---------------------------------------------------------------------------
// K6b: combine partials -> delta = upd - Vmean. One block per bh.
// ---------------------------------------------------------------------------
__global__ __launch_bounds__(256) void attn_combine(
    const float* __restrict__ psums, const float* __restrict__ pacc,
    const float* __restrict__ VmeanRaw, float* __restrict__ delta)
{
    const int bh = blockIdx.x;
    __shared__ float winv[NTOP];
    if (threadIdx.x < NTOP) {
        float s = 0.f;
        for (int c = 0; c < NCHUNK; ++c)
            s += psums[((size_t)bh * NCHUNK + c) * NTOP + threadIdx.x];
        winv[threadIdx.x] = 1.0f / s;
    }
    __syncthreads();
    const int d = threadIdx.x & 63, g = threadIdx.x >> 6;
    const float vm = VmeanRaw[bh * DHD + d] * (1.0f / (float)LSEQ);
    for (int q = g; q < NTOP; q += 4) {
        float a = 0.f;
        for (int c = 0; c < NCHUNK; ++c)
            a += pacc[(((size_t)bh * NCHUNK + c) * NTOP + q) * DHD + d];
        delta[((size_t)bh * NTOP + q) * DHD + d] = a * winv[q] - vm;
    }
}

// ---------------------------------------------------------------------------
// K7: final output rows.
// ---------------------------------------------------------------------------
__global__ __launch_bounds__(256) void out_kernel(
    const float* __restrict__ meanout, const unsigned* __restrict__ headmask,
    const unsigned char* __restrict__ slot, const float* __restrict__ delta,
    const float* __restrict__ Wo, float* __restrict__ out)
{
    const int rowg = blockIdx.x;
    const int b = rowg >> 11, lloc = rowg & (LSEQ - 1);
    const unsigned mask = headmask[rowg];

    __shared__ float dl[NH][DHD];
    for (int h = 0; h < NH; ++h) {
        if ((mask >> h) & 1) {
            if (threadIdx.x < DHD) {
                const int bh = b * NH + h;
                const int u = slot[bh * LSEQ + lloc];
                dl[h][threadIdx.x] = delta[((size_t)bh * NTOP + u) * DHD + threadIdx.x];
            }
        }
    }
    __syncthreads();

#pragma unroll
    for (int i = 0; i < 2; ++i) {
        const int n = threadIdx.x + i * 256;
        float val = meanout[b * DMODEL + n];
        unsigned mm = mask;
        while (mm) {
            const int h = __ffs(mm) - 1;
            mm &= mm - 1;
            const float* wr = Wo + (size_t)n * DMODEL + h * DHD;
            float a = 0.f;
#pragma unroll
            for (int dd = 0; dd < DHD; ++dd) a = fmaf(dl[h][dd], wr[dd], a);
            val += a;
        }
        out[(size_t)rowg * DMODEL + n] = val;
    }
}

// ---------------------------------------------------------------------------
extern "C" void kernel_launch(void* const* d_in, const int* in_sizes, int n_in,
                              void* d_out, int out_size, void* d_ws, size_t ws_size,
                              hipStream_t stream)
{
    (void)in_sizes; (void)n_in; (void)out_size; (void)ws_size;
    const float* x     = (const float*)d_in[0];
    const float* ctxin = (const float*)d_in[1];
    const float* Wq    = (const float*)d_in[2];
    const float* bq    = (const float*)d_in[3];
    const float* Wk    = (const float*)d_in[4];
    const float* bk    = (const float*)d_in[5];
    const float* Wv    = (const float*)d_in[6];
    const float* bv    = (const float*)d_in[7];
    const float* Wo    = (const float*)d_in[8];
    const float* bo    = (const float*)d_in[9];
    const int*   idxs  = (const int*)d_in[10];
    float* out = (float*)d_out;

    char* ws = (char*)d_ws;
    size_t off = 0;
    auto alloc = [&](size_t bytes) -> void* {
        void* p = ws + off;
        off += (bytes + 255) & ~(size_t)255;
        return p;
    };

    const size_t qkv_bytes = (size_t)BATCH * NH * LSEQ * DHD * sizeof(float);
    float*         Qt       = (float*)alloc(qkv_bytes);
    float*         Kt       = (float*)alloc(qkv_bytes);
    float*         Vt       = (float*)alloc(qkv_bytes);
    float*         Mbuf     = (float*)alloc((size_t)BATCH * NH * LSEQ * sizeof(float));
    float*         VmeanRaw = (float*)alloc((size_t)BATCH * NH * DHD * sizeof(float));
    float*         meanout  = (float*)alloc((size_t)BATCH * DMODEL * sizeof(float));
    float*         delta    = (float*)alloc((size_t)BATCH * NH * NTOP * DHD * sizeof(float));
    int*           topidx   = (int*)alloc((size_t)BATCH * NH * NTOP * sizeof(int));
    unsigned*      headmask = (unsigned*)alloc((size_t)BATCH * LSEQ * sizeof(unsigned));
    unsigned char* slot     = (unsigned char*)alloc((size_t)BATCH * NH * LSEQ);
    float*         psums    = (float*)alloc((size_t)BATCH * NH * NCHUNK * NTOP * sizeof(float));
    float*         pacc     = (float*)alloc((size_t)BATCH * NH * NCHUNK * NTOP * DHD * sizeof(float));

    qkv_gemm_f32<<<dim3(8192 / 128, DMODEL / 128, 3), 256, 0, stream>>>(
        x, ctxin, Wq, bq, Wk, bk, Wv, bv, Qt, Kt, Vt);

    score_kernel<<<(BATCH * NH * LSEQ) / 4, 256, 0, stream>>>(Qt, Kt, idxs, Mbuf);

    hipMemsetAsync(headmask, 0, (size_t)BATCH * LSEQ * sizeof(unsigned), stream);
    hipMemsetAsync(VmeanRaw, 0, (size_t)BATCH * NH * DHD * sizeof(float), stream);

    topk_kernel<<<BATCH * NH, 256, 0, stream>>>(Mbuf, topidx, headmask, slot);

    vmean_kernel<<<dim3(BATCH * NH, LSEQ / 256), 256, 0, stream>>>(Vt, VmeanRaw);

    meanout_kernel<<<BATCH, 256, 0, stream>>>(VmeanRaw, Wo, bo, meanout);

    attn_partial<<<dim3(BATCH * NH, NCHUNK), 256, 0, stream>>>(
        Qt, Kt, Vt, topidx, psums, pacc);

    attn_combine<<<BATCH * NH, 256, 0, stream>>>(psums, pacc, VmeanRaw, delta);

    out_kernel<<<BATCH * LSEQ, 256, 0, stream>>>(meanout, headmask, slot, delta, Wo, out);
}